// Round 4
// baseline (32.524 us; speedup 1.0000x reference)
//
#include <hip/hip_runtime.h>
#include <math.h>

#define PATCH 512
#define SLACK 64
#define STEP  (PATCH - SLACK)   /* 448 */
#define HS    (SLACK / 2)       /* 32  */

typedef float f32x4 __attribute__((ext_vector_type(4)));

struct Geom {
    int p0, p1;     // patch top-left in image
    int gi0, gi1;   // paste dest top-left in image
    int ph, pw;     // paste height/width
};

// All geometry from make_grid + paste_coords. `i` is an SGPR value, so this
// compiles to SALU.
__device__ __forceinline__ Geom compute_geom(int i, int H, int W) {
    const int gh = (H - PATCH + STEP - 1) / STEP + 1;
    const int gw = (W - PATCH + STEP - 1) / STEP + 1;
    const int r = (unsigned)i / (unsigned)gw;
    const int c = (unsigned)i % (unsigned)gw;
    const int gyr = min(PATCH + r * STEP, H);
    const int gxc = min(PATCH + c * STEP, W);
    Geom g;
    g.p0 = max(gyr - PATCH, 0);
    g.p1 = max(gxc - PATCH, 0);
    const int gy_m2 = min(PATCH + (gh - 2) * STEP, H);
    const int gx_m2 = min(PATCH + (gw - 2) * STEP, W);
    const int gy_m1 = min(PATCH + (gh - 1) * STEP, H);
    const int gx_m1 = min(PATCH + (gw - 1) * STEP, W);
    const int lh0 = (gy_m2 - (gy_m1 - PATCH)) / 2;
    const int lh1 = (gx_m2 - (gx_m1 - PATCH)) / 2;
    const int di0 = (r == 0) ? 0 : ((r == gh - 1) ? lh0 : HS);
    const int di1 = (c == 0) ? 0 : ((c == gw - 1) ? lh1 : HS);
    const int di2 = (r < gh - 1) ? (PATCH - HS) : PATCH;
    const int di3 = (c < gw - 1) ? (PATCH - HS) : PATCH;
    g.gi0 = g.p0 + di0;
    g.gi1 = g.p1 + di1;
    g.ph  = di2 - di0;
    g.pw  = di3 - di1;
    return g;
}

// conv3x3 + bias + sigmoid at patch coords (py,px); zero-pad at patch border.
__device__ __forceinline__ float conv_px(const int* __restrict__ x,
                                         const float* __restrict__ Wt,
                                         float bias, int py, int px,
                                         int p0, int p1, int W) {
    const float inv255 = 1.0f / 255.0f;
    float acc = bias;
#pragma unroll
    for (int ky = 0; ky < 3; ++ky) {
        const int ppy = py + ky - 1;
        if (ppy < 0 || ppy >= PATCH) continue;
        const int ih = p0 + ppy;
#pragma unroll
        for (int kx = 0; kx < 3; ++kx) {
            const int ppx = px + kx - 1;
            if (ppx < 0 || ppx >= PATCH) continue;
            const int iw = p1 + ppx;
            const int* __restrict__ xp = x + ((size_t)ih * W + iw) * 3;
            acc += Wt[0 * 9 + ky * 3 + kx] * ((float)xp[0] * inv255)
                 + Wt[1 * 9 + ky * 3 + kx] * ((float)xp[1] * inv255)
                 + Wt[2 * 9 + ky * 3 + kx] * ((float)xp[2] * inv255);
        }
    }
    return 1.0f / (1.0f + expf(-acc));
}

// ---------------------------------------------------------------------------
// One block per output row. Fast path (rows outside the paste rect): 4x
// unrolled nontemporal float4 copy — 4 outstanding coalesced loads before any
// store, no L2 write-allocate. Slow path only for the ph rect rows.
// ---------------------------------------------------------------------------
__global__ __launch_bounds__(256) void fused_kernel(
        const int* __restrict__ x, const float* __restrict__ y,
        const float* __restrict__ Wt, const float* __restrict__ bp,
        const int* __restrict__ ip, float* __restrict__ out,
        int H, int W) {
    const int row = blockIdx.x;
    const int t = threadIdx.x;
    const int i = __builtin_amdgcn_readfirstlane(ip[0]);  // uniform -> SGPR
    const Geom g = compute_geom(i, H, W);                 // SALU
    const int w4 = W >> 2;
    const size_t rowbase = (size_t)row * w4;
    const f32x4* __restrict__ y4 = (const f32x4*)y + rowbase;
    f32x4* __restrict__ o4 = (f32x4*)out + rowbase;

    const bool rowin = (row >= g.gi0) && (row < g.gi0 + g.ph);  // scalar
    if (!rowin) {
        if (i > 0) {
            int q = t;
            for (; q + 768 < w4; q += 1024) {
                f32x4 v0 = __builtin_nontemporal_load(y4 + q);
                f32x4 v1 = __builtin_nontemporal_load(y4 + q + 256);
                f32x4 v2 = __builtin_nontemporal_load(y4 + q + 512);
                f32x4 v3 = __builtin_nontemporal_load(y4 + q + 768);
                __builtin_nontemporal_store(v0, o4 + q);
                __builtin_nontemporal_store(v1, o4 + q + 256);
                __builtin_nontemporal_store(v2, o4 + q + 512);
                __builtin_nontemporal_store(v3, o4 + q + 768);
            }
            for (; q < w4; q += 256)
                __builtin_nontemporal_store(__builtin_nontemporal_load(y4 + q),
                                            o4 + q);
        } else {
            const f32x4 z = {0.f, 0.f, 0.f, 0.f};
            for (int q = t; q < w4; q += 256)
                __builtin_nontemporal_store(z, o4 + q);
        }
        return;
    }

    // row intersects the paste rectangle
    const float bias = bp[0];
    const int cl = g.gi1, cr = g.gi1 + g.pw;   // [cl, cr) = rect columns
    for (int q = t; q < w4; q += 256) {
        const int c0 = q << 2;
        f32x4 v;
        if (c0 + 3 < cl || c0 >= cr) {
            if (i > 0) v = __builtin_nontemporal_load(y4 + q);
            else       v = (f32x4){0.f, 0.f, 0.f, 0.f};
        } else {
#pragma unroll
            for (int j = 0; j < 4; ++j) {
                const int col = c0 + j;
                if (col >= cl && col < cr) {
                    v[j] = conv_px(x, Wt, bias, row - g.p0, col - g.p1,
                                   g.p0, g.p1, W);
                } else {
                    v[j] = (i > 0) ? y[(size_t)row * W + col] : 0.f;
                }
            }
        }
        __builtin_nontemporal_store(v, o4 + q);
    }
}

// ---------------------------------------------------------------------------
extern "C" void kernel_launch(void* const* d_in, const int* in_sizes, int n_in,
                              void* d_out, int out_size, void* d_ws, size_t ws_size,
                              hipStream_t stream) {
    const int*   x  = (const int*)d_in[0];    // (1,H,W,3) int32
    const float* y  = (const float*)d_in[1];  // (1,1,H,W) f32
    const float* Wt = (const float*)d_in[2];  // (1,3,3,3) f32
    const float* b  = (const float*)d_in[3];  // (1,) f32
    const int*   ip = (const int*)d_in[4];    // scalar i
    float* out = (float*)d_out;

    // square plane: H = W = sqrt(out_size)
    int H = 1;
    while ((long long)(H + 1) * (H + 1) <= (long long)out_size) ++H;
    const int Wd = H;

    fused_kernel<<<dim3(H), dim3(256), 0, stream>>>(x, y, Wt, b, ip, out, H, Wd);
}

// Round 5
// 28.300 us; speedup vs baseline: 1.1492x; 1.1492x over previous
//
#include <hip/hip_runtime.h>
#include <math.h>

#define PATCH 512
#define SLACK 64
#define STEP  (PATCH - SLACK)   /* 448 */
#define HS    (SLACK / 2)       /* 32  */

typedef float f32x4 __attribute__((ext_vector_type(4)));

struct Geom {
    int p0, p1;     // patch top-left in image
    int gi0, gi1;   // paste dest top-left in image
    int ph, pw;     // paste height/width
};

// make_grid + paste_coords geometry from uniform scalar i (SALU).
__device__ __forceinline__ Geom compute_geom(int i, int H, int W) {
    const int gh = (H - PATCH + STEP - 1) / STEP + 1;
    const int gw = (W - PATCH + STEP - 1) / STEP + 1;
    const int r = (unsigned)i / (unsigned)gw;
    const int c = (unsigned)i % (unsigned)gw;
    const int gyr = min(PATCH + r * STEP, H);
    const int gxc = min(PATCH + c * STEP, W);
    Geom g;
    g.p0 = max(gyr - PATCH, 0);
    g.p1 = max(gxc - PATCH, 0);
    const int gy_m2 = min(PATCH + (gh - 2) * STEP, H);
    const int gx_m2 = min(PATCH + (gw - 2) * STEP, W);
    const int gy_m1 = min(PATCH + (gh - 1) * STEP, H);
    const int gx_m1 = min(PATCH + (gw - 1) * STEP, W);
    const int lh0 = (gy_m2 - (gy_m1 - PATCH)) / 2;
    const int lh1 = (gx_m2 - (gx_m1 - PATCH)) / 2;
    const int di0 = (r == 0) ? 0 : ((r == gh - 1) ? lh0 : HS);
    const int di1 = (c == 0) ? 0 : ((c == gw - 1) ? lh1 : HS);
    const int di2 = (r < gh - 1) ? (PATCH - HS) : PATCH;
    const int di3 = (c < gw - 1) ? (PATCH - HS) : PATCH;
    g.gi0 = g.p0 + di0;
    g.gi1 = g.p1 + di1;
    g.ph  = di2 - di0;
    g.pw  = di3 - di1;
    return g;
}

// conv3x3 + bias + sigmoid at patch coords (py,px); zero-pad at patch border.
__device__ __forceinline__ float conv_px(const int* __restrict__ x,
                                         const float* __restrict__ Wt,
                                         float bias, int py, int px,
                                         int p0, int p1, int W) {
    const float inv255 = 1.0f / 255.0f;
    float acc = bias;
#pragma unroll
    for (int ky = 0; ky < 3; ++ky) {
        const int ppy = py + ky - 1;
        if (ppy < 0 || ppy >= PATCH) continue;
        const int ih = p0 + ppy;
#pragma unroll
        for (int kx = 0; kx < 3; ++kx) {
            const int ppx = px + kx - 1;
            if (ppx < 0 || ppx >= PATCH) continue;
            const int iw = p1 + ppx;
            const int* __restrict__ xp = x + ((size_t)ih * W + iw) * 3;
            acc += Wt[0 * 9 + ky * 3 + kx] * ((float)xp[0] * inv255)
                 + Wt[1 * 9 + ky * 3 + kx] * ((float)xp[1] * inv255)
                 + Wt[2 * 9 + ky * 3 + kx] * ((float)xp[2] * inv255);
        }
    }
    return 1.0f / (1.0f + expf(-acc));
}

// ---------------------------------------------------------------------------
// Single dispatch, block-specialized:
//   blocks [0, CB): flat 1:1 float4 copy of the base plane (round-1 pattern,
//     the fastest measured). Blocks are row-uniform (W/4 % 256 == 0), so the
//     rect test is a scalar branch; only straddling float4s go element-wise,
//     and rect-interior elements are skipped (conv blocks own them).
//   blocks [CB, CB+CONVB): conv3x3+sigmoid over the paste rect.
// Writes are disjoint -> no inter-block ordering needed.
// ---------------------------------------------------------------------------
__global__ __launch_bounds__(256) void fused_one(
        const int* __restrict__ x, const float* __restrict__ y,
        const float* __restrict__ Wt, const float* __restrict__ bp,
        const int* __restrict__ ip, float* __restrict__ out,
        int H, int W, int CB) {
    const int i = __builtin_amdgcn_readfirstlane(ip[0]);  // uniform -> SGPR
    const Geom g = compute_geom(i, H, W);                 // SALU
    const int b = blockIdx.x;
    const int t = threadIdx.x;
    const int w4 = W >> 2;

    if (b < CB) {
        const int q = b * 256 + t;          // float4 index in plane
        const int sh = 31 - __clz(w4);      // w4 is pow2 (1024 for W=4096)
        const int row = q >> sh;
        const int c0 = (q & (w4 - 1)) << 2; // first pixel column
        const f32x4* __restrict__ y4 = (const f32x4*)y;
        f32x4* __restrict__ o4 = (f32x4*)out;

        const bool rowin = (row >= g.gi0) && (row < g.gi0 + g.ph); // uniform
        const int cl = g.gi1, cr = g.gi1 + g.pw;
        // block's column span: blockCol0 = (b*256 & (w4-1))<<2, width 1024
        const int bc0 = ((b * 256) & (w4 - 1)) << 2;
        if (!rowin || (bc0 + 1023 < cl) || (bc0 >= cr)) {
            // pure copy / zero path
            f32x4 v;
            if (i > 0) v = y4[q];
            else       v = (f32x4){0.f, 0.f, 0.f, 0.f};
            o4[q] = v;
        } else {
            // row intersects rect and block column-span overlaps it
            if (c0 + 3 < cl || c0 >= cr) {
                f32x4 v;
                if (i > 0) v = y4[q];
                else       v = (f32x4){0.f, 0.f, 0.f, 0.f};
                o4[q] = v;
            } else if (c0 >= cl && c0 + 3 < cr) {
                // fully inside rect: conv blocks own these elements
            } else {
                // straddles rect boundary: element-wise, skip inside elems
#pragma unroll
                for (int j = 0; j < 4; ++j) {
                    const int col = c0 + j;
                    if (col < cl || col >= cr) {
                        out[(size_t)row * W + col] =
                            (i > 0) ? y[(size_t)row * W + col] : 0.f;
                    }
                }
            }
        }
        return;
    }

    // ---- conv blocks ----
    const int p = (b - CB) * 256 + t;       // linear pixel in rect
    const int np = g.ph * g.pw;
    if (p >= np) return;
    const int pr = (unsigned)p / (unsigned)g.pw;
    const int pc = (unsigned)p % (unsigned)g.pw;
    const float bias = bp[0];
    const float v = conv_px(x, Wt, bias,
                            (g.gi0 - g.p0) + pr, (g.gi1 - g.p1) + pc,
                            g.p0, g.p1, W);
    out[(size_t)(g.gi0 + pr) * W + (g.gi1 + pc)] = v;
}

// ---------------------------------------------------------------------------
extern "C" void kernel_launch(void* const* d_in, const int* in_sizes, int n_in,
                              void* d_out, int out_size, void* d_ws, size_t ws_size,
                              hipStream_t stream) {
    const int*   x  = (const int*)d_in[0];    // (1,H,W,3) int32
    const float* y  = (const float*)d_in[1];  // (1,1,H,W) f32
    const float* Wt = (const float*)d_in[2];  // (1,3,3,3) f32
    const float* b  = (const float*)d_in[3];  // (1,) f32
    const int*   ip = (const int*)d_in[4];    // scalar i
    float* out = (float*)d_out;

    // square plane: H = W = sqrt(out_size)
    int H = 1;
    while ((long long)(H + 1) * (H + 1) <= (long long)out_size) ++H;
    const int Wd = H;

    const int CB = (H * (Wd >> 2)) / 256;        // copy blocks (flat 1:1)
    const int CONVB = (PATCH * PATCH) / 256;     // worst-case rect coverage
    fused_one<<<dim3(CB + CONVB), dim3(256), 0, stream>>>(
        x, y, Wt, b, ip, out, H, Wd, CB);
}